// Round 1
// baseline (1304.860 us; speedup 1.0000x reference)
//
#include <hip/hip_runtime.h>
#include <stdint.h>

// CA model constants (match reference)
#define BB 8
#define CC 16
#define HH_ 128
#define WW 128
#define HIDN 128
#define HWSZ (HH_ * WW)          // 16384
#define NPIX (BB * HWSZ)         // 131072
#define NSTEPS 16

// JAX PRNG mode: 1 = jax_threefry_partitionable (modern default), 0 = legacy
#define JAX_THREEFRY_PARTITIONABLE 1

// ---------------------------------------------------------------------------
// Threefry-2x32, 20 rounds — exact JAX implementation.
// ---------------------------------------------------------------------------
__host__ __device__ inline void threefry2x32(uint32_t k0, uint32_t k1,
                                             uint32_t x0, uint32_t x1,
                                             uint32_t* o0, uint32_t* o1) {
  uint32_t ks0 = k0, ks1 = k1, ks2 = k0 ^ k1 ^ 0x1BD11BDAu;
  uint32_t ks[3] = {ks0, ks1, ks2};
  const uint32_t rots[2][4] = {{13u, 15u, 26u, 6u}, {17u, 29u, 16u, 24u}};
  x0 += ks[0];
  x1 += ks[1];
#pragma unroll
  for (int g = 0; g < 5; ++g) {
    const uint32_t* r = rots[g & 1];
#pragma unroll
    for (int i = 0; i < 4; ++i) {
      x0 += x1;
      x1 = (x1 << r[i]) | (x1 >> (32u - r[i]));
      x1 ^= x0;
    }
    x0 += ks[(g + 1) % 3];
    x1 += ks[(g + 2) % 3] + (uint32_t)(g + 1);
  }
  *o0 = x0;
  *o1 = x1;
}

// mask bit for flat pixel index g under step key (key0,key1)
__device__ __forceinline__ float jax_mask_bit(uint32_t key0, uint32_t key1, int g) {
  uint32_t t0, t1;
#if JAX_THREEFRY_PARTITIONABLE
  // counter = (hi, lo) of 64-bit flat index; bits = t0 ^ t1
  threefry2x32(key0, key1, 0u, (uint32_t)g, &t0, &t1);
  uint32_t bits = t0 ^ t1;
#else
  // legacy: iota(N) split in halves; N = 131072, half = 65536
  uint32_t bits;
  if (g < 65536) {
    threefry2x32(key0, key1, (uint32_t)g, (uint32_t)(g + 65536), &t0, &t1);
    bits = t0;
  } else {
    threefry2x32(key0, key1, (uint32_t)(g - 65536), (uint32_t)g, &t0, &t1);
    bits = t1;
  }
#endif
  float u = __uint_as_float((bits >> 9) | 0x3f800000u) - 1.0f;
  return (u < 0.5f) ? 1.0f : 0.0f;
}

// ---------------------------------------------------------------------------
// Kernel A: sobel perception + MLP + mask -> writes "new" state to nxt
// ---------------------------------------------------------------------------
__global__ __launch_bounds__(256, 2) void ca_step_mlp(
    const float* __restrict__ cur, const float* __restrict__ w1,
    const float* __restrict__ b1, const float* __restrict__ w2,
    const float* __restrict__ b2, float* __restrict__ nxt,
    uint32_t key0, uint32_t key1) {
  __shared__ float lw1[HIDN * 48];   // 24576 B, row-major [hid][48]
  __shared__ float lb1[HIDN];
  __shared__ float lw2t[HIDN * CC];  // 8192 B, transposed [hid][out]
  __shared__ float lb2[CC];

  for (int i = threadIdx.x; i < HIDN * 48; i += 256) lw1[i] = w1[i];
  for (int i = threadIdx.x; i < HIDN; i += 256) lb1[i] = b1[i];
  for (int i = threadIdx.x; i < HIDN * CC; i += 256) {
    int hh = i / CC, o = i % CC;
    lw2t[i] = w2[o * HIDN + hh];
  }
  for (int i = threadIdx.x; i < CC; i += 256) lb2[i] = b2[i];
  __syncthreads();

  const int g = blockIdx.x * 256 + threadIdx.x;  // 0..NPIX-1
  const int b = g >> 14;
  const int hw = g & (HWSZ - 1);
  const int h = hw >> 7;
  const int w = hw & (WW - 1);

  const bool hu = h > 0, hd = h < HH_ - 1, wl = w > 0, wr = w < WW - 1;
  const int du = hu ? -WW : 0;
  const int dd = hd ? WW : 0;
  const int dl = wl ? -1 : 0;
  const int dr = wr ? 1 : 0;

  const float* xb = cur + (size_t)b * CC * HWSZ + hw;

  // perception: [ident(16) | sobel_x(16) | sobel_y(16)]
  float p[48];
#pragma unroll
  for (int c = 0; c < CC; ++c) {
    const float* xc = xb + c * HWSZ;
    float n00 = xc[du + dl]; if (!(hu && wl)) n00 = 0.f;
    float n01 = xc[du];      if (!hu)         n01 = 0.f;
    float n02 = xc[du + dr]; if (!(hu && wr)) n02 = 0.f;
    float n10 = xc[dl];      if (!wl)         n10 = 0.f;
    float n11 = xc[0];
    float n12 = xc[dr];      if (!wr)         n12 = 0.f;
    float n20 = xc[dd + dl]; if (!(hd && wl)) n20 = 0.f;
    float n21 = xc[dd];      if (!hd)         n21 = 0.f;
    float n22 = xc[dd + dr]; if (!(hd && wr)) n22 = 0.f;
    p[c] = n11;
    // cross-correlation with SOBEL_X = [[1,0,-1],[2,0,-2],[1,0,-1]]/8
    p[16 + c] = (n00 - n02 + 2.f * (n10 - n12) + n20 - n22) * 0.125f;
    // SOBEL_Y = [[1,2,1],[0,0,0],[-1,-2,-1]]/8
    p[32 + c] = (n00 + 2.f * n01 + n02 - n20 - 2.f * n21 - n22) * 0.125f;
  }

  float diff[CC];
#pragma unroll
  for (int o = 0; o < CC; ++o) diff[o] = lb2[o];

  for (int hh = 0; hh < HIDN; ++hh) {
    const float4* wrow = (const float4*)(lw1 + hh * 48);
    float a0 = lb1[hh], a1 = 0.f, a2 = 0.f, a3 = 0.f;
#pragma unroll
    for (int q = 0; q < 3; ++q) {
      float4 w0 = wrow[q * 4 + 0];
      float4 w1v = wrow[q * 4 + 1];
      float4 w2v = wrow[q * 4 + 2];
      float4 w3 = wrow[q * 4 + 3];
      const int base = q * 16;
      a0 = fmaf(w0.x, p[base + 0], a0);
      a0 = fmaf(w0.y, p[base + 1], a0);
      a0 = fmaf(w0.z, p[base + 2], a0);
      a0 = fmaf(w0.w, p[base + 3], a0);
      a1 = fmaf(w1v.x, p[base + 4], a1);
      a1 = fmaf(w1v.y, p[base + 5], a1);
      a1 = fmaf(w1v.z, p[base + 6], a1);
      a1 = fmaf(w1v.w, p[base + 7], a1);
      a2 = fmaf(w2v.x, p[base + 8], a2);
      a2 = fmaf(w2v.y, p[base + 9], a2);
      a2 = fmaf(w2v.z, p[base + 10], a2);
      a2 = fmaf(w2v.w, p[base + 11], a2);
      a3 = fmaf(w3.x, p[base + 12], a3);
      a3 = fmaf(w3.y, p[base + 13], a3);
      a3 = fmaf(w3.z, p[base + 14], a3);
      a3 = fmaf(w3.w, p[base + 15], a3);
    }
    float acc = (a0 + a1) + (a2 + a3);
    acc = fmaxf(acc, 0.f);
    const float4* w2row = (const float4*)(lw2t + hh * CC);
#pragma unroll
    for (int o4 = 0; o4 < 4; ++o4) {
      float4 wv = w2row[o4];
      diff[o4 * 4 + 0] = fmaf(wv.x, acc, diff[o4 * 4 + 0]);
      diff[o4 * 4 + 1] = fmaf(wv.y, acc, diff[o4 * 4 + 1]);
      diff[o4 * 4 + 2] = fmaf(wv.z, acc, diff[o4 * 4 + 2]);
      diff[o4 * 4 + 3] = fmaf(wv.w, acc, diff[o4 * 4 + 3]);
    }
  }

  const float m = jax_mask_bit(key0, key1, g);

  float* nb = nxt + (size_t)b * CC * HWSZ + hw;
#pragma unroll
  for (int c = 0; c < CC; ++c) {
    nb[c * HWSZ] = fmaf(diff[c], m, p[c]);  // exact: m in {0,1}
  }
}

// ---------------------------------------------------------------------------
// Kernel B: 3x3 max-pool on alpha (ch 3), alive gate, write next state
// ---------------------------------------------------------------------------
__global__ __launch_bounds__(256) void ca_step_alive(
    const float* __restrict__ nw, float* __restrict__ out) {
  const int g = blockIdx.x * 256 + threadIdx.x;
  const int b = g >> 14;
  const int hw = g & (HWSZ - 1);
  const int h = hw >> 7;
  const int w = hw & (WW - 1);
  const bool hu = h > 0, hd = h < HH_ - 1, wl = w > 0, wr = w < WW - 1;

  const float* ab = nw + ((size_t)b * CC + 3) * HWSZ + hw;
  float pooled = ab[0];
  if (hu) {
    pooled = fmaxf(pooled, ab[-WW]);
    if (wl) pooled = fmaxf(pooled, ab[-WW - 1]);
    if (wr) pooled = fmaxf(pooled, ab[-WW + 1]);
  }
  if (hd) {
    pooled = fmaxf(pooled, ab[WW]);
    if (wl) pooled = fmaxf(pooled, ab[WW - 1]);
    if (wr) pooled = fmaxf(pooled, ab[WW + 1]);
  }
  if (wl) pooled = fmaxf(pooled, ab[-1]);
  if (wr) pooled = fmaxf(pooled, ab[1]);

  const float alive = (pooled > 0.1f) ? 1.0f : 0.0f;

  const float* nb = nw + (size_t)b * CC * HWSZ + hw;
  float* ob = out + (size_t)b * CC * HWSZ + hw;
#pragma unroll
  for (int c = 0; c < CC; ++c) ob[c * HWSZ] = nb[c * HWSZ] * alive;
}

// ---------------------------------------------------------------------------
extern "C" void kernel_launch(void* const* d_in, const int* in_sizes, int n_in,
                              void* d_out, int out_size, void* d_ws,
                              size_t ws_size, hipStream_t stream) {
  const float* x = (const float*)d_in[0];
  const float* w1 = (const float*)d_in[1];
  const float* b1 = (const float*)d_in[2];
  const float* w2 = (const float*)d_in[3];
  const float* b2 = (const float*)d_in[4];
  // d_in[5] = n_steps (16) — fixed at compile time

  float* out = (float*)d_out;
  float* nbuf = (float*)d_ws;  // needs NPIX*CC*4 = 8 MB

  // step keys from split(key(42), 16)
  uint32_t k0s[NSTEPS], k1s[NSTEPS];
#if JAX_THREEFRY_PARTITIONABLE
  for (int s = 0; s < NSTEPS; ++s)
    threefry2x32(0u, 42u, 0u, (uint32_t)s, &k0s[s], &k1s[s]);
#else
  {
    uint32_t bits[32];
    for (int i = 0; i < 16; ++i) {
      uint32_t o0, o1;
      threefry2x32(0u, 42u, (uint32_t)i, (uint32_t)(i + 16), &o0, &o1);
      bits[i] = o0;
      bits[i + 16] = o1;
    }
    for (int s = 0; s < NSTEPS; ++s) {
      k0s[s] = bits[2 * s];
      k1s[s] = bits[2 * s + 1];
    }
  }
#endif

  dim3 grid(NPIX / 256), block(256);
  for (int s = 0; s < NSTEPS; ++s) {
    const float* src = (s == 0) ? x : out;
    ca_step_mlp<<<grid, block, 0, stream>>>(src, w1, b1, w2, b2, nbuf,
                                            k0s[s], k1s[s]);
    ca_step_alive<<<grid, block, 0, stream>>>(nbuf, out);
  }
}

// Round 2
// 833.033 us; speedup vs baseline: 1.5664x; 1.5664x over previous
//
#include <hip/hip_runtime.h>
#include <stdint.h>

// CA model constants (match reference)
#define BB 8
#define CC 16
#define HH_ 128
#define WW 128
#define HIDN 128
#define HWSZ (HH_ * WW)          // 16384
#define NPIX (BB * HWSZ)         // 131072
#define NSTEPS 16

// ---------------------------------------------------------------------------
// Threefry-2x32, 20 rounds — exact JAX implementation (partitionable mode).
// ---------------------------------------------------------------------------
__host__ __device__ inline void threefry2x32(uint32_t k0, uint32_t k1,
                                             uint32_t x0, uint32_t x1,
                                             uint32_t* o0, uint32_t* o1) {
  uint32_t ks[3] = {k0, k1, k0 ^ k1 ^ 0x1BD11BDAu};
  const uint32_t rots[2][4] = {{13u, 15u, 26u, 6u}, {17u, 29u, 16u, 24u}};
  x0 += ks[0];
  x1 += ks[1];
#pragma unroll
  for (int g = 0; g < 5; ++g) {
    const uint32_t* r = rots[g & 1];
#pragma unroll
    for (int i = 0; i < 4; ++i) {
      x0 += x1;
      x1 = (x1 << r[i]) | (x1 >> (32u - r[i]));
      x1 ^= x0;
    }
    x0 += ks[(g + 1) % 3];
    x1 += ks[(g + 2) % 3] + (uint32_t)(g + 1);
  }
  *o0 = x0;
  *o1 = x1;
}

__device__ __forceinline__ float jax_mask_bit(uint32_t key0, uint32_t key1, int g) {
  uint32_t t0, t1;
  threefry2x32(key0, key1, 0u, (uint32_t)g, &t0, &t1);
  uint32_t bits = t0 ^ t1;
  float u = __uint_as_float((bits >> 9) | 0x3f800000u) - 1.0f;
  return (u < 0.5f) ? 1.0f : 0.0f;
}

// ---------------------------------------------------------------------------
// Kernel A: sobel perception + MLP + mask -> writes "new" state to nxt
// w1/b1/b2 read via wave-uniform global loads (scalar pipe, s_load);
// only transposed w2 staged in LDS (8 KB, 4 broadcast ds_read_b128 per hh).
// ---------------------------------------------------------------------------
__global__ __launch_bounds__(256, 2) void ca_step_mlp(
    const float* __restrict__ cur, const float* __restrict__ w1,
    const float* __restrict__ b1, const float* __restrict__ w2,
    const float* __restrict__ b2, float* __restrict__ nxt,
    uint32_t key0, uint32_t key1) {
  __shared__ float lw2t[HIDN * CC];  // 8192 B, [hh][o]

  // stage w2 transposed: coalesced global read, scattered LDS write (one-time)
  for (int i = threadIdx.x; i < HIDN * CC; i += 256) {
    int o = i >> 7;           // i / 128
    int hh = i & (HIDN - 1);  // i % 128
    lw2t[hh * CC + o] = w2[i];
  }
  __syncthreads();

  const int g = blockIdx.x * 256 + threadIdx.x;  // 0..NPIX-1
  const int b = g >> 14;
  const int hw = g & (HWSZ - 1);
  const int h = hw >> 7;
  const int w = hw & (WW - 1);

  const bool hu = h > 0, hd = h < HH_ - 1, wl = w > 0, wr = w < WW - 1;
  const int du = hu ? -WW : 0;
  const int dd = hd ? WW : 0;
  const int dl = wl ? -1 : 0;
  const int dr = wr ? 1 : 0;

  const float* xb = cur + (size_t)b * CC * HWSZ + hw;

  // perception: [ident(16) | sobel_x(16) | sobel_y(16)]
  float p[48];
#pragma unroll
  for (int c = 0; c < CC; ++c) {
    const float* xc = xb + c * HWSZ;
    float n00 = xc[du + dl]; if (!(hu && wl)) n00 = 0.f;
    float n01 = xc[du];      if (!hu)         n01 = 0.f;
    float n02 = xc[du + dr]; if (!(hu && wr)) n02 = 0.f;
    float n10 = xc[dl];      if (!wl)         n10 = 0.f;
    float n11 = xc[0];
    float n12 = xc[dr];      if (!wr)         n12 = 0.f;
    float n20 = xc[dd + dl]; if (!(hd && wl)) n20 = 0.f;
    float n21 = xc[dd];      if (!hd)         n21 = 0.f;
    float n22 = xc[dd + dr]; if (!(hd && wr)) n22 = 0.f;
    p[c] = n11;
    p[16 + c] = (n00 - n02 + 2.f * (n10 - n12) + n20 - n22) * 0.125f;
    p[32 + c] = (n00 + 2.f * n01 + n02 - n20 - 2.f * n21 - n22) * 0.125f;
  }

  float diff[CC];
#pragma unroll
  for (int o = 0; o < CC; ++o) diff[o] = b2[o];  // uniform -> s_load

  for (int hh = 0; hh < HIDN; ++hh) {
    // wave-uniform address -> compiler emits s_load_dwordx4 (scalar pipe)
    const float4* wrow = (const float4*)(w1 + hh * 48);
    float a0 = b1[hh], a1 = 0.f, a2 = 0.f, a3 = 0.f;
#pragma unroll
    for (int q = 0; q < 3; ++q) {
      float4 w0 = wrow[q * 4 + 0];
      float4 w1v = wrow[q * 4 + 1];
      float4 w2v = wrow[q * 4 + 2];
      float4 w3 = wrow[q * 4 + 3];
      const int base = q * 16;
      a0 = fmaf(w0.x, p[base + 0], a0);
      a0 = fmaf(w0.y, p[base + 1], a0);
      a0 = fmaf(w0.z, p[base + 2], a0);
      a0 = fmaf(w0.w, p[base + 3], a0);
      a1 = fmaf(w1v.x, p[base + 4], a1);
      a1 = fmaf(w1v.y, p[base + 5], a1);
      a1 = fmaf(w1v.z, p[base + 6], a1);
      a1 = fmaf(w1v.w, p[base + 7], a1);
      a2 = fmaf(w2v.x, p[base + 8], a2);
      a2 = fmaf(w2v.y, p[base + 9], a2);
      a2 = fmaf(w2v.z, p[base + 10], a2);
      a2 = fmaf(w2v.w, p[base + 11], a2);
      a3 = fmaf(w3.x, p[base + 12], a3);
      a3 = fmaf(w3.y, p[base + 13], a3);
      a3 = fmaf(w3.z, p[base + 14], a3);
      a3 = fmaf(w3.w, p[base + 15], a3);
    }
    float acc = (a0 + a1) + (a2 + a3);
    acc = fmaxf(acc, 0.f);
    const float4* w2row = (const float4*)(lw2t + hh * CC);
#pragma unroll
    for (int o4 = 0; o4 < 4; ++o4) {
      float4 wv = w2row[o4];
      diff[o4 * 4 + 0] = fmaf(wv.x, acc, diff[o4 * 4 + 0]);
      diff[o4 * 4 + 1] = fmaf(wv.y, acc, diff[o4 * 4 + 1]);
      diff[o4 * 4 + 2] = fmaf(wv.z, acc, diff[o4 * 4 + 2]);
      diff[o4 * 4 + 3] = fmaf(wv.w, acc, diff[o4 * 4 + 3]);
    }
  }

  const float m = jax_mask_bit(key0, key1, g);

  float* nb = nxt + (size_t)b * CC * HWSZ + hw;
#pragma unroll
  for (int c = 0; c < CC; ++c) {
    nb[c * HWSZ] = fmaf(diff[c], m, p[c]);  // exact: m in {0,1}
  }
}

// ---------------------------------------------------------------------------
// Kernel B: 3x3 max-pool on alpha (ch 3), alive gate, write next state
// ---------------------------------------------------------------------------
__global__ __launch_bounds__(256) void ca_step_alive(
    const float* __restrict__ nw, float* __restrict__ out) {
  const int g = blockIdx.x * 256 + threadIdx.x;
  const int b = g >> 14;
  const int hw = g & (HWSZ - 1);
  const int h = hw >> 7;
  const int w = hw & (WW - 1);
  const bool hu = h > 0, hd = h < HH_ - 1, wl = w > 0, wr = w < WW - 1;

  const float* ab = nw + ((size_t)b * CC + 3) * HWSZ + hw;
  float pooled = ab[0];
  if (hu) {
    pooled = fmaxf(pooled, ab[-WW]);
    if (wl) pooled = fmaxf(pooled, ab[-WW - 1]);
    if (wr) pooled = fmaxf(pooled, ab[-WW + 1]);
  }
  if (hd) {
    pooled = fmaxf(pooled, ab[WW]);
    if (wl) pooled = fmaxf(pooled, ab[WW - 1]);
    if (wr) pooled = fmaxf(pooled, ab[WW + 1]);
  }
  if (wl) pooled = fmaxf(pooled, ab[-1]);
  if (wr) pooled = fmaxf(pooled, ab[1]);

  const float alive = (pooled > 0.1f) ? 1.0f : 0.0f;

  const float* nb = nw + (size_t)b * CC * HWSZ + hw;
  float* ob = out + (size_t)b * CC * HWSZ + hw;
#pragma unroll
  for (int c = 0; c < CC; ++c) ob[c * HWSZ] = nb[c * HWSZ] * alive;
}

// ---------------------------------------------------------------------------
extern "C" void kernel_launch(void* const* d_in, const int* in_sizes, int n_in,
                              void* d_out, int out_size, void* d_ws,
                              size_t ws_size, hipStream_t stream) {
  const float* x = (const float*)d_in[0];
  const float* w1 = (const float*)d_in[1];
  const float* b1 = (const float*)d_in[2];
  const float* w2 = (const float*)d_in[3];
  const float* b2 = (const float*)d_in[4];
  // d_in[5] = n_steps (16) — fixed at compile time

  float* out = (float*)d_out;
  float* nbuf = (float*)d_ws;  // NPIX*CC*4 = 8 MB scratch

  // step keys from split(key(42), 16), partitionable threefry
  uint32_t k0s[NSTEPS], k1s[NSTEPS];
  for (int s = 0; s < NSTEPS; ++s)
    threefry2x32(0u, 42u, 0u, (uint32_t)s, &k0s[s], &k1s[s]);

  dim3 grid(NPIX / 256), block(256);
  for (int s = 0; s < NSTEPS; ++s) {
    const float* src = (s == 0) ? x : out;
    ca_step_mlp<<<grid, block, 0, stream>>>(src, w1, b1, w2, b2, nbuf,
                                            k0s[s], k1s[s]);
    ca_step_alive<<<grid, block, 0, stream>>>(nbuf, out);
  }
}